// Round 6
// baseline (191.204 us; speedup 1.0000x reference)
//
#include <hip/hip_runtime.h>
#include <hip/hip_bf16.h>
#include <math.h>

#define Bg   128
#define Nn   64
#define Tt   256
#define INF  320      // Nn + Tt
#define Hd   256
#define OUTD 128
#define Ee   2016     // Nn*(Nn-1)/2
#define TOTE (Bg*Ee)  // 258048
#define SCOLS 576     // padded 514 -> 9*64 so GEMM2 tiles exactly
#define MROWS 8192    // Bg*Nn

typedef __attribute__((ext_vector_type(8))) short bf16x8;
typedef __attribute__((ext_vector_type(4))) float f32x4;

static __device__ __forceinline__ ushort f2bf(float v) {
    __hip_bfloat16 h = __float2bfloat16(v);
    return *(ushort*)&h;
}
static __device__ __forceinline__ unsigned fkey(float x) {
    unsigned b = __float_as_uint(x);
    return (b & 0x80000000u) ? ~b : (b | 0x80000000u);
}
static __device__ __forceinline__ float fkeyinv(unsigned k) {
    unsigned b = (k & 0x80000000u) ? (k ^ 0x80000000u) : ~k;
    return __uint_as_float(b);
}

// ---------------- prep: Wg->bf16, packed Wcat->bf16, edge LUT, red init ----------------
#define CVT_N (INF * Hd)                  // 81920
#define PACK_N (Hd * SCOLS)               // 147456
__global__ void k_prep(const float* __restrict__ Wg, const float* __restrict__ Wm,
                       const float* __restrict__ Wv, const float* __restrict__ Ww,
                       ushort* __restrict__ Wgb, ushort* __restrict__ Wcat,
                       int2* __restrict__ lut, unsigned* __restrict__ red) {
    int idx = blockIdx.x * 256 + threadIdx.x;
    if (idx == 0) { red[0] = 0u; red[1] = 0u; }
    if (idx < CVT_N) {
        Wgb[idx] = f2bf(Wg[idx]);
        return;
    }
    idx -= CVT_N;
    if (idx < PACK_N) {
        int k = idx / SCOLS, col = idx - k * SCOLS;
        float v = 0.f;
        if (col < 128)       v = Wm[k * 128 + col];
        else if (col < 256)  v = Wm[(256 + k) * 128 + (col - 128)];
        else if (col < 384)  v = Wv[k * 128 + (col - 256)];
        else if (col < 512)  v = Wv[(256 + k) * 128 + (col - 384)];
        else if (col == 512) v = Ww[k];
        else if (col == 513) v = Ww[256 + k];
        Wcat[idx] = f2bf(v);
        return;
    }
    idx -= PACK_N;
    if (idx >= Ee) return;
    int r = 0;
    while ((r + 1) * (127 - (r + 1)) / 2 <= idx) ++r;
    int c = r + 1 + (idx - r * (127 - r) / 2);
    lut[idx] = make_int2(r, c);
}

// ---------------- prefix-mean aggregation via wave64 scan -> bf16 ----------------
// grid (128, 80), block 256 = 4 waves; wave w handles feature f, lane = node j.
__global__ __launch_bounds__(256) void k_agg(const float* __restrict__ topo,
                                             const float* __restrict__ temp,
                                             ushort* __restrict__ agg) {
    int b = blockIdx.x;
    int w = threadIdx.x >> 6, lane = threadIdx.x & 63;
    int f = blockIdx.y * 4 + w;
    float x = (f < Nn) ? topo[(size_t)(b * Nn + lane) * Nn + f]
                       : temp[(size_t)(b * Nn + lane) * Tt + (f - Nn)];
    float incl = x;
    #pragma unroll
    for (int o = 1; o < 64; o <<= 1) {
        float t = __shfl_up(incl, o);
        if (lane >= o) incl += t;
    }
    float excl = incl - x;
    float v = lane ? excl / (float)lane : 0.f;
    agg[(size_t)(b * Nn + lane) * INF + f] = f2bf(v);
}

// ---------------- bf16 MFMA GEMM, 128x64 tile, BK=32 ----------------
// A: MxK bf16 row-major, B: KxN bf16 row-major. 256 thr = 4 waves x 32 rows.
// transC=0: C row-major (Cb bf16 if non-null, else Cf fp32).
// transC=1: Cf fp32 transposed, leading dim MROWS (Cf[col][row]).
__global__ __launch_bounds__(256) void k_gemm_mfma(const ushort* __restrict__ A,
                                                   const ushort* __restrict__ B,
                                                   const float* __restrict__ bias,
                                                   ushort* __restrict__ Cb,
                                                   float* __restrict__ Cf,
                                                   int N, int K, int relu, int transC) {
    __shared__ ushort Asl[128 * 32];
    __shared__ ushort Bsl[64 * 32];   // transposed: Bsl[n][k]
    const int tid = threadIdx.x;
    const int w = tid >> 6, lane = tid & 63;
    const int quad = lane >> 4, r16 = lane & 15;
    const int m0 = blockIdx.y * 128, n0 = blockIdx.x * 64;
    const int arow = tid >> 1, aseg = tid & 1;     // 2 threads/row, 16 elems each
    const int bk = tid >> 3, bseg = tid & 7;
    f32x4 acc[2][4] = {};

    for (int k0 = 0; k0 < K; k0 += 32) {
        const ushort* ap = A + (size_t)(m0 + arow) * K + k0 + aseg * 16;
        uint4 av0 = ((const uint4*)ap)[0];
        uint4 av1 = ((const uint4*)ap)[1];
        *(uint4*)(Asl + arow * 32 + aseg * 16)     = av0;
        *(uint4*)(Asl + arow * 32 + aseg * 16 + 8) = av1;
        int bcol = n0 + bseg * 8;
        uint4 bvv = *(const uint4*)(B + (size_t)(k0 + bk) * N + bcol);
        ushort tmp[8];
        *(uint4*)tmp = bvv;
        #pragma unroll
        for (int t = 0; t < 8; ++t) Bsl[(bseg * 8 + t) * 32 + bk] = tmp[t];
        __syncthreads();

        bf16x8 af0 = *(const bf16x8*)(Asl + (w * 32 + r16) * 32 + quad * 8);
        bf16x8 af1 = *(const bf16x8*)(Asl + (w * 32 + 16 + r16) * 32 + quad * 8);
        #pragma unroll
        for (int ns = 0; ns < 4; ++ns) {
            bf16x8 bfr = *(const bf16x8*)(Bsl + (ns * 16 + r16) * 32 + quad * 8);
            acc[0][ns] = __builtin_amdgcn_mfma_f32_16x16x32_bf16(af0, bfr, acc[0][ns], 0, 0, 0);
            acc[1][ns] = __builtin_amdgcn_mfma_f32_16x16x32_bf16(af1, bfr, acc[1][ns], 0, 0, 0);
        }
        __syncthreads();
    }

    #pragma unroll
    for (int ms = 0; ms < 2; ++ms) {
        const int row0 = m0 + w * 32 + ms * 16 + quad * 4;
        #pragma unroll
        for (int ns = 0; ns < 4; ++ns) {
            f32x4 a = acc[ms][ns];
            int col = n0 + ns * 16 + r16;
            float vv[4];
            #pragma unroll
            for (int i = 0; i < 4; ++i) {
                float v = a[i] + (bias ? bias[col] : 0.f);
                if (relu) v = fmaxf(v, 0.f);
                vv[i] = v;
            }
            if (transC) {
                *(float4*)(Cf + (size_t)col * MROWS + row0) = make_float4(vv[0], vv[1], vv[2], vv[3]);
            } else {
                #pragma unroll
                for (int i = 0; i < 4; ++i) {
                    int row = row0 + i;
                    if (Cb) Cb[(size_t)row * N + col] = f2bf(vv[i]);
                    else    Cf[(size_t)row * N + col] = vv[i];
                }
            }
        }
    }
}

// ---------------- quadrant x t-slice edge partial kernel ----------------
// 1536 blocks = 128 graphs x 3 quadrants x 4 t-slices. LDS 16 KB.
static __device__ __forceinline__ float eterm(float pm, float qm, float pv, float qv) {
    float m = pm + qm;
    float x = pv + qv;
    float sp = fmaxf(x, 0.f) + __logf(1.f + __expf(-fabsf(x)));
    return m * m * __builtin_amdgcn_rcpf(sp + 1.01e-6f);
}

__global__ __launch_bounds__(256) void k_edge3(const float* __restrict__ ST,
                                               const float* __restrict__ bm,
                                               const float* __restrict__ bv,
                                               float* __restrict__ partial) {
    __shared__ float L[4][32][32];
    const int blk = blockIdx.x;
    const int tq = blk & 3;
    const int q  = (blk >> 2) % 3;
    const int b  = blk / 12;
    const int ih = (q == 2) ? 1 : 0, jh = (q == 0) ? 0 : 1;
    const int toff = tq * 32;
    const int tid = threadIdx.x;

    #pragma unroll
    for (int rep = 0; rep < 16; ++rep) {
        int idx = tid + 256 * rep;             // 0..4095
        int arr = idx >> 10;                   // 0:Pm(i) 1:Qm(j)+bm 2:Pv(i) 3:Qv(j)+bv
        int t = (idx >> 5) & 31, n = idx & 31;
        int side = (arr & 1) ? jh : ih;
        float v = ST[(size_t)(arr * 128 + toff + t) * MROWS + b * 64 + side * 32 + n];
        if (arr == 1) v += bm[toff + t];
        if (arr == 3) v += bv[toff + t];
        L[arr][t][n] = v;
    }
    __syncthreads();

    const int ti = tid >> 4, tj = tid & 15;
    const int i0 = 2 * ti, j0 = 2 * tj;
    float a00 = 0.f, a01 = 0.f, a10 = 0.f, a11 = 0.f;

    #pragma unroll 8
    for (int t = 0; t < 32; ++t) {
        float2 mi = *(const float2*)&L[0][t][i0];
        float2 mj = *(const float2*)&L[1][t][j0];
        float2 vi = *(const float2*)&L[2][t][i0];
        float2 vj = *(const float2*)&L[3][t][j0];
        a00 += eterm(mi.x, mj.x, vi.x, vj.x);
        a01 += eterm(mi.x, mj.y, vi.x, vj.y);
        a10 += eterm(mi.y, mj.x, vi.y, vj.x);
        a11 += eterm(mi.y, mj.y, vi.y, vj.y);
    }

    float accs[2][2] = {{a00, a01}, {a10, a11}};
    float* p = partial + (size_t)tq * TOTE + (size_t)b * Ee;
    #pragma unroll
    for (int di = 0; di < 2; ++di) {
        #pragma unroll
        for (int dj = 0; dj < 2; ++dj) {
            int gi = ih * 32 + i0 + di, gj = jh * 32 + j0 + dj;
            if (gi >= gj) continue;
            p[(gi * (127 - gi)) / 2 + (gj - gi - 1)] = accs[di][dj];
        }
    }
}

// ---------------- edge finalize: sim + logit + global-max atomic ----------------
// TOTE = 1008 * 256 exactly.
__global__ __launch_bounds__(256) void k_fin(const float* __restrict__ partial,
                                             const float* __restrict__ ST,
                                             const int2* __restrict__ lut,
                                             const float* __restrict__ bw,
                                             const float* __restrict__ gu,
                                             float* __restrict__ sim,
                                             float* __restrict__ lgt,
                                             unsigned* __restrict__ red) {
    __shared__ float sm[256];
    int e = blockIdx.x * 256 + threadIdx.x;
    int b = e / Ee, el = e - b * Ee;
    int2 rc = lut[el];
    float acc = partial[e] + partial[TOTE + e] + partial[2 * TOTE + e] + partial[3 * TOTE + e];
    float se = __expf(acc * (-1.f / 256.f));   // exp(-0.5*acc/128)
    float wr = ST[(size_t)512 * MROWS + b * 64 + rc.x]
             + ST[(size_t)513 * MROWS + b * 64 + rc.y] + bw[0];
    float w  = __builtin_amdgcn_rcpf(1.f + __expf(-wr));
    float g  = -__logf(-__logf(gu[e]));
    float L  = (w + g) * 2.0f;   // / TEMPERATURE(=0.5)
    sim[e] = se;
    lgt[e] = L;
    sm[threadIdx.x] = L; __syncthreads();
    for (int s = 128; s; s >>= 1) {
        if (threadIdx.x < s) sm[threadIdx.x] = fmaxf(sm[threadIdx.x], sm[threadIdx.x + s]);
        __syncthreads();
    }
    if (!threadIdx.x) atomicMax(&red[0], fkey(sm[0]));
}

// ---------------- softmax denominator ----------------
__global__ void k_red2(const float* __restrict__ lgt, unsigned* __restrict__ red) {
    __shared__ float sm[256];
    float M = fkeyinv(red[0]);
    float a = 0.f;
    for (int i = blockIdx.x * 256 + threadIdx.x; i < TOTE; i += 256 * 256)
        a += __expf(lgt[i] - M);
    sm[threadIdx.x] = a; __syncthreads();
    for (int s = 128; s; s >>= 1) {
        if (threadIdx.x < s) sm[threadIdx.x] += sm[threadIdx.x + s];
        __syncthreads();
    }
    if (!threadIdx.x) atomicAdd((float*)&red[1], sm[0]);
}

// ---------------- final scatter (also zero-fills) ----------------
__global__ void k_out(const float* __restrict__ sim, const float* __restrict__ lgt,
                      const unsigned* __restrict__ red, float* __restrict__ out) {
    int idx = blockIdx.x * 256 + threadIdx.x;
    if (idx >= Bg * Nn * Nn) return;
    int b = idx >> 12;
    int rem = idx & 4095;
    int r = rem >> 6, c = rem & 63;
    float v = 0.f;
    if (c > r) {
        int e = b * Ee + (r * (127 - r)) / 2 + (c - r - 1);
        float M = fkeyinv(red[0]);
        float Sinv = __builtin_amdgcn_rcpf(__uint_as_float(red[1]));
        v = sim[e] * __expf(lgt[e] - M) * Sinv;
    }
    out[idx] = v;
}

extern "C" void kernel_launch(void* const* d_in, const int* in_sizes, int n_in,
                              void* d_out, int out_size, void* d_ws, size_t ws_size,
                              hipStream_t stream) {
    const float* topo = (const float*)d_in[0];
    const float* temp = (const float*)d_in[1];
    const float* gu   = (const float*)d_in[2];
    const float* Wg   = (const float*)d_in[3];
    const float* bg   = (const float*)d_in[4];
    const float* Wm   = (const float*)d_in[5];
    const float* bm   = (const float*)d_in[6];
    const float* Wv   = (const float*)d_in[7];
    const float* bv   = (const float*)d_in[8];
    const float* Ww   = (const float*)d_in[9];
    const float* bw   = (const float*)d_in[10];
    float* out = (float*)d_out;

    char* ws = (char*)d_ws;
    size_t off = 0;
    auto carve = [&](size_t bytes) { char* p = ws + off; off = (off + bytes + 255) & ~(size_t)255; return p; };

    // r1 hosts aggb (bf16, 5.2 MB) pre-GEMM1, then S_T[576][8192] f32 (18.9 MB).
    char*   r1    = carve((size_t)SCOLS * MROWS * 4);
    float*  ST    = (float*)r1;
    ushort* aggb  = (ushort*)r1;
    ushort* hb    = (ushort*)carve((size_t)MROWS * Hd * 2);      // 4.19 MB
    ushort* Wgb   = (ushort*)carve((size_t)INF * Hd * 2);        // 0.16 MB
    ushort* Wcatb = (ushort*)carve((size_t)Hd * SCOLS * 2);      // 0.29 MB
    float*  part  = (float*)carve((size_t)4 * TOTE * 4);         // 4.13 MB
    float*  sim   = (float*)carve((size_t)TOTE * 4);             // 1.03 MB
    float*  lgt   = (float*)carve((size_t)TOTE * 4);             // 1.03 MB
    int2*   lut   = (int2*)carve((size_t)Ee * 8);
    unsigned* red = (unsigned*)carve(256);

    k_prep<<<(CVT_N + PACK_N + Ee + 255) / 256, 256, 0, stream>>>(
        Wg, Wm, Wv, Ww, Wgb, Wcatb, lut, red);
    k_agg<<<dim3(Bg, INF / 4), 256, 0, stream>>>(topo, temp, aggb);
    // GEMM1: hb[8192,256] = relu(aggb[8192,320] @ Wgb[320,256] + bg)
    k_gemm_mfma<<<dim3(Hd / 64, MROWS / 128), 256, 0, stream>>>(
        aggb, Wgb, bg, hb, nullptr, Hd, INF, 1, 0);
    // GEMM2: ST[576][8192] = (hb[8192,256] @ Wcatb[256,576])^T
    k_gemm_mfma<<<dim3(SCOLS / 64, MROWS / 128), 256, 0, stream>>>(
        hb, Wcatb, nullptr, nullptr, ST, SCOLS, Hd, 0, 1);
    k_edge3<<<Bg * 12, 256, 0, stream>>>(ST, bm, bv, part);
    k_fin<<<TOTE / 256, 256, 0, stream>>>(part, ST, lut, bw, gu, sim, lgt, red);
    k_red2<<<256, 256, 0, stream>>>(lgt, red);
    k_out<<<(Bg * Nn * Nn + 255) / 256, 256, 0, stream>>>(sim, lgt, red, out);
}

// Round 7
// 162.026 us; speedup vs baseline: 1.1801x; 1.1801x over previous
//
#include <hip/hip_runtime.h>
#include <hip/hip_bf16.h>
#include <math.h>

#define Bg   128
#define Nn   64
#define Tt   256
#define INF  320      // Nn + Tt
#define Hd   256
#define OUTD 128
#define Ee   2016     // Nn*(Nn-1)/2
#define TOTE (Bg*Ee)  // 258048
#define SCOLS 576     // padded 514 -> 9*64 so GEMM2 tiles exactly
#define MROWS 8192    // Bg*Nn

typedef __attribute__((ext_vector_type(8))) short bf16x8;
typedef __attribute__((ext_vector_type(4))) float f32x4;

static __device__ __forceinline__ ushort f2bf(float v) {
    __hip_bfloat16 h = __float2bfloat16(v);
    return *(ushort*)&h;
}
static __device__ __forceinline__ unsigned fkey(float x) {
    unsigned b = __float_as_uint(x);
    return (b & 0x80000000u) ? ~b : (b | 0x80000000u);
}
static __device__ __forceinline__ float fkeyinv(unsigned k) {
    unsigned b = (k & 0x80000000u) ? (k ^ 0x80000000u) : ~k;
    return __uint_as_float(b);
}

// ---------------- prep: Wg->bf16, packed Wcat->bf16, ebias, red init ----------------
#define CVT_N (INF * Hd)                  // 81920
#define PACK_N (Hd * SCOLS)               // 147456
__global__ void k_prep(const float* __restrict__ Wg, const float* __restrict__ Wm,
                       const float* __restrict__ Wv, const float* __restrict__ Ww,
                       const float* __restrict__ bm, const float* __restrict__ bv,
                       const float* __restrict__ bw,
                       ushort* __restrict__ Wgb, ushort* __restrict__ Wcat,
                       float* __restrict__ ebias, unsigned* __restrict__ red) {
    int idx = blockIdx.x * 256 + threadIdx.x;
    if (idx == 0) { red[0] = 0u; red[1] = 0u; }
    if (idx < CVT_N) {
        Wgb[idx] = f2bf(Wg[idx]);
        return;
    }
    idx -= CVT_N;
    if (idx < PACK_N) {
        int k = idx / SCOLS, col = idx - k * SCOLS;
        float v = 0.f;
        if (col < 128)       v = Wm[k * 128 + col];
        else if (col < 256)  v = Wm[(256 + k) * 128 + (col - 128)];
        else if (col < 384)  v = Wv[k * 128 + (col - 256)];
        else if (col < 512)  v = Wv[(256 + k) * 128 + (col - 384)];
        else if (col == 512) v = Ww[k];
        else if (col == 513) v = Ww[256 + k];
        Wcat[idx] = f2bf(v);
        return;
    }
    idx -= PACK_N;
    if (idx >= SCOLS) return;
    float e = 0.f;
    if (idx < 128)                    e = bm[idx];
    else if (idx >= 256 && idx < 384) e = bv[idx - 256];
    else if (idx == 512)              e = bw[0];
    ebias[idx] = e;
}

// ---------------- prefix-mean aggregation: wave64 scan + LDS transpose store ----------------
// grid (128, 80), block 256 = 4 waves; wave w: feature f = by*4+w, lane = node j.
__global__ __launch_bounds__(256) void k_agg(const float* __restrict__ topo,
                                             const float* __restrict__ temp,
                                             ushort* __restrict__ agg) {
    __shared__ float Ltr[64][5];
    int b = blockIdx.x;
    int w = threadIdx.x >> 6, lane = threadIdx.x & 63;
    int f = blockIdx.y * 4 + w;
    float x = (f < Nn) ? topo[(size_t)(b * Nn + lane) * Nn + f]
                       : temp[(size_t)(b * Nn + lane) * Tt + (f - Nn)];
    float incl = x;
    #pragma unroll
    for (int o = 1; o < 64; o <<= 1) {
        float t = __shfl_up(incl, o);
        if (lane >= o) incl += t;
    }
    float excl = incl - x;
    Ltr[lane][w] = lane ? excl / (float)lane : 0.f;
    __syncthreads();
    int node = threadIdx.x >> 2, fi = threadIdx.x & 3;
    agg[(size_t)(b * Nn + node) * INF + blockIdx.y * 4 + fi] = f2bf(Ltr[node][fi]);
}

// ---------------- bf16 MFMA GEMM, 64x64 tile, BK=32 (R5-proven) ----------------
// transC=0: C row-major (Cb bf16 w/ bias+relu, else Cf fp32).
// transC=1: Cf fp32 transposed (Cf[col][row], ld=MROWS), bias added per col.
__global__ __launch_bounds__(256) void k_gemm_mfma(const ushort* __restrict__ A,
                                                   const ushort* __restrict__ B,
                                                   const float* __restrict__ bias,
                                                   ushort* __restrict__ Cb,
                                                   float* __restrict__ Cf,
                                                   int N, int K, int relu, int transC) {
    __shared__ ushort Asl[64 * 32];
    __shared__ ushort Bsl[64 * 32];   // transposed: Bsl[n][k]
    const int tid = threadIdx.x;
    const int w = tid >> 6, lane = tid & 63;
    const int quad = lane >> 4, r16 = lane & 15;
    const int m0 = blockIdx.y * 64, n0 = blockIdx.x * 64;
    const int arow = tid >> 2, aseg = tid & 3;
    const int bk = tid >> 3, bseg = tid & 7;
    f32x4 acc0 = {0,0,0,0}, acc1 = {0,0,0,0}, acc2 = {0,0,0,0}, acc3 = {0,0,0,0};

    for (int k0 = 0; k0 < K; k0 += 32) {
        uint4 av = *(const uint4*)(A + (size_t)(m0 + arow) * K + k0 + aseg * 8);
        *(uint4*)(Asl + arow * 32 + aseg * 8) = av;
        int bcol = n0 + bseg * 8;
        uint4 bvv = *(const uint4*)(B + (size_t)(k0 + bk) * N + bcol);
        ushort tmp[8];
        *(uint4*)tmp = bvv;
        #pragma unroll
        for (int t = 0; t < 8; ++t) Bsl[(bseg * 8 + t) * 32 + bk] = tmp[t];
        __syncthreads();

        bf16x8 af = *(const bf16x8*)(Asl + (w * 16 + r16) * 32 + quad * 8);
        bf16x8 bf0 = *(const bf16x8*)(Bsl + (0 * 16 + r16) * 32 + quad * 8);
        bf16x8 bf1 = *(const bf16x8*)(Bsl + (1 * 16 + r16) * 32 + quad * 8);
        bf16x8 bf2 = *(const bf16x8*)(Bsl + (2 * 16 + r16) * 32 + quad * 8);
        bf16x8 bf3 = *(const bf16x8*)(Bsl + (3 * 16 + r16) * 32 + quad * 8);
        acc0 = __builtin_amdgcn_mfma_f32_16x16x32_bf16(af, bf0, acc0, 0, 0, 0);
        acc1 = __builtin_amdgcn_mfma_f32_16x16x32_bf16(af, bf1, acc1, 0, 0, 0);
        acc2 = __builtin_amdgcn_mfma_f32_16x16x32_bf16(af, bf2, acc2, 0, 0, 0);
        acc3 = __builtin_amdgcn_mfma_f32_16x16x32_bf16(af, bf3, acc3, 0, 0, 0);
        __syncthreads();
    }

    const int row0 = m0 + w * 16 + quad * 4;
    #pragma unroll
    for (int ns = 0; ns < 4; ++ns) {
        f32x4 a = (ns == 0) ? acc0 : (ns == 1) ? acc1 : (ns == 2) ? acc2 : acc3;
        int col = n0 + ns * 16 + r16;
        float bb = bias ? bias[col] : 0.f;
        float vv[4];
        #pragma unroll
        for (int i = 0; i < 4; ++i) {
            float v = a[i] + bb;
            if (relu) v = fmaxf(v, 0.f);
            vv[i] = v;
        }
        if (transC) {
            *(float4*)(Cf + (size_t)col * MROWS + row0) = make_float4(vv[0], vv[1], vv[2], vv[3]);
        } else {
            #pragma unroll
            for (int i = 0; i < 4; ++i) {
                int row = row0 + i;
                if (Cb) Cb[(size_t)row * N + col] = f2bf(vv[i]);
                else    Cf[(size_t)row * N + col] = vv[i];
            }
        }
    }
}

// ---------------- fused edge kernel: group-pair tiles, full-t, final outputs ----------------
// 1280 blocks = 128 graphs x 10 group-pairs (4 groups of 16 nodes, gi<=gj).
// LDS [4][16 nodes][132 t] f32 (+1 KB reduce buf) = 34 KB -> 4 blocks/CU.
// Thread = one (i,j) pair, reduces all 128 t via ds_read_b128. Writes sim/lgt + atomicMax.
static __device__ __forceinline__ float eterm(float pm, float qm, float pv, float qv) {
    float m = pm + qm;
    float x = pv + qv;
    float sp = fmaxf(x, 0.f) + __logf(1.f + __expf(-fabsf(x)));
    return m * m * __builtin_amdgcn_rcpf(sp + 1.01e-6f);
}

__global__ __launch_bounds__(256) void k_edge4(const float* __restrict__ ST,
                                               const float* __restrict__ gu,
                                               float* __restrict__ sim,
                                               float* __restrict__ lgt,
                                               unsigned* __restrict__ red) {
    __shared__ float L[4][16][132];
    __shared__ float sm[256];
    const int p = blockIdx.x % 10, b = blockIdx.x / 10;
    // group pairs (g0<=g1) over 4 groups
    const int G0v[10] = {0,0,0,0,1,1,1,2,2,3};
    const int G1v[10] = {0,1,2,3,1,2,3,2,3,3};
    const int g0 = G0v[p], g1 = G1v[p];
    const int tid = threadIdx.x;

    // stage: arr 0=Pm(i-grp) 1=Qm(j-grp) 2=Pv(i-grp) 3=Qv(j-grp); biases pre-folded.
    #pragma unroll
    for (int rep = 0; rep < 8; ++rep) {
        int it = tid + 256 * rep;              // 0..2047
        int arr = it >> 9;                     // 0..3
        int c = (it >> 2) & 127, nq = it & 3;  // t-row, node-quad
        int g = (arr & 1) ? g1 : g0;
        float4 v = *(const float4*)&ST[(size_t)(arr * 128 + c) * MROWS + b * 64 + g * 16 + nq * 4];
        L[arr][nq * 4 + 0][c] = v.x;
        L[arr][nq * 4 + 1][c] = v.y;
        L[arr][nq * 4 + 2][c] = v.z;
        L[arr][nq * 4 + 3][c] = v.w;
    }
    __syncthreads();

    const int i = tid >> 4, j = tid & 15;
    float acc = 0.f;
    #pragma unroll 4
    for (int t = 0; t < 128; t += 4) {
        float4 mi = *(const float4*)&L[0][i][t];
        float4 mj = *(const float4*)&L[1][j][t];
        float4 vi = *(const float4*)&L[2][i][t];
        float4 vj = *(const float4*)&L[3][j][t];
        acc += eterm(mi.x, mj.x, vi.x, vj.x);
        acc += eterm(mi.y, mj.y, vi.y, vj.y);
        acc += eterm(mi.z, mj.z, vi.z, vj.z);
        acc += eterm(mi.w, mj.w, vi.w, vj.w);
    }

    const int ni = g0 * 16 + i, nj = g1 * 16 + j;
    float lv = -INFINITY;
    if (ni < nj) {
        int e = b * Ee + (ni * (127 - ni)) / 2 + (nj - ni - 1);
        float se = __expf(acc * (-1.f / 256.f));   // exp(-0.5*acc/128)
        float wr = ST[(size_t)512 * MROWS + b * 64 + ni]
                 + ST[(size_t)513 * MROWS + b * 64 + nj];   // bw folded into row 512
        float w  = __builtin_amdgcn_rcpf(1.f + __expf(-wr));
        float g  = -__logf(-__logf(gu[e]));
        lv = (w + g) * 2.0f;   // / TEMPERATURE(=0.5)
        sim[e] = se;
        lgt[e] = lv;
    }
    sm[tid] = lv; __syncthreads();
    for (int s = 128; s; s >>= 1) {
        if (tid < s) sm[tid] = fmaxf(sm[tid], sm[tid + s]);
        __syncthreads();
    }
    if (!tid) atomicMax(&red[0], fkey(sm[0]));
}

// ---------------- softmax denominator ----------------
__global__ void k_red2(const float* __restrict__ lgt, unsigned* __restrict__ red) {
    __shared__ float sm[256];
    float M = fkeyinv(red[0]);
    float a = 0.f;
    for (int i = blockIdx.x * 256 + threadIdx.x; i < TOTE; i += 256 * 256)
        a += __expf(lgt[i] - M);
    sm[threadIdx.x] = a; __syncthreads();
    for (int s = 128; s; s >>= 1) {
        if (threadIdx.x < s) sm[threadIdx.x] += sm[threadIdx.x + s];
        __syncthreads();
    }
    if (!threadIdx.x) atomicAdd((float*)&red[1], sm[0]);
}

// ---------------- final scatter (also zero-fills) ----------------
__global__ void k_out(const float* __restrict__ sim, const float* __restrict__ lgt,
                      const unsigned* __restrict__ red, float* __restrict__ out) {
    int idx = blockIdx.x * 256 + threadIdx.x;
    if (idx >= Bg * Nn * Nn) return;
    int b = idx >> 12;
    int rem = idx & 4095;
    int r = rem >> 6, c = rem & 63;
    float v = 0.f;
    if (c > r) {
        int e = b * Ee + (r * (127 - r)) / 2 + (c - r - 1);
        float M = fkeyinv(red[0]);
        float Sinv = __builtin_amdgcn_rcpf(__uint_as_float(red[1]));
        v = sim[e] * __expf(lgt[e] - M) * Sinv;
    }
    out[idx] = v;
}

extern "C" void kernel_launch(void* const* d_in, const int* in_sizes, int n_in,
                              void* d_out, int out_size, void* d_ws, size_t ws_size,
                              hipStream_t stream) {
    const float* topo = (const float*)d_in[0];
    const float* temp = (const float*)d_in[1];
    const float* gu   = (const float*)d_in[2];
    const float* Wg   = (const float*)d_in[3];
    const float* bg   = (const float*)d_in[4];
    const float* Wm   = (const float*)d_in[5];
    const float* bm   = (const float*)d_in[6];
    const float* Wv   = (const float*)d_in[7];
    const float* bv   = (const float*)d_in[8];
    const float* Ww   = (const float*)d_in[9];
    const float* bw   = (const float*)d_in[10];
    float* out = (float*)d_out;

    char* ws = (char*)d_ws;
    size_t off = 0;
    auto carve = [&](size_t bytes) { char* p = ws + off; off = (off + bytes + 255) & ~(size_t)255; return p; };

    // r1 hosts aggb (bf16, 5.2 MB) pre-GEMM1, then S_T[576][8192] f32 (18.9 MB).
    char*   r1    = carve((size_t)SCOLS * MROWS * 4);
    float*  ST    = (float*)r1;
    ushort* aggb  = (ushort*)r1;
    ushort* hb    = (ushort*)carve((size_t)MROWS * Hd * 2);      // 4.19 MB
    ushort* Wgb   = (ushort*)carve((size_t)INF * Hd * 2);        // 0.16 MB
    ushort* Wcatb = (ushort*)carve((size_t)Hd * SCOLS * 2);      // 0.29 MB
    float*  ebias = (float*)carve((size_t)SCOLS * 4);
    float*  sim   = (float*)carve((size_t)TOTE * 4);             // 1.03 MB
    float*  lgt   = (float*)carve((size_t)TOTE * 4);             // 1.03 MB
    unsigned* red = (unsigned*)carve(256);

    k_prep<<<(CVT_N + PACK_N + SCOLS + 255) / 256, 256, 0, stream>>>(
        Wg, Wm, Wv, Ww, bm, bv, bw, Wgb, Wcatb, ebias, red);
    k_agg<<<dim3(Bg, INF / 4), 256, 0, stream>>>(topo, temp, aggb);
    // GEMM1: hb[8192,256] = relu(aggb[8192,320] @ Wgb[320,256] + bg)
    k_gemm_mfma<<<dim3(Hd / 64, MROWS / 64), 256, 0, stream>>>(
        aggb, Wgb, bg, hb, nullptr, Hd, INF, 1, 0);
    // GEMM2: ST[576][8192] = (hb[8192,256] @ Wcatb[256,576] + ebias)^T
    k_gemm_mfma<<<dim3(SCOLS / 64, MROWS / 64), 256, 0, stream>>>(
        hb, Wcatb, ebias, nullptr, ST, SCOLS, Hd, 0, 1);
    k_edge4<<<Bg * 10, 256, 0, stream>>>(ST, gu, sim, lgt, red);
    k_red2<<<256, 256, 0, stream>>>(lgt, red);
    k_out<<<(Bg * Nn * Nn + 255) / 256, 256, 0, stream>>>(sim, lgt, red, out);
}

// Round 8
// 146.917 us; speedup vs baseline: 1.3014x; 1.1028x over previous
//
#include <hip/hip_runtime.h>
#include <hip/hip_bf16.h>
#include <math.h>

#define Bg   128
#define Nn   64
#define Tt   256
#define INF  320      // Nn + Tt
#define Hd   256
#define OUTD 128
#define Ee   2016     // Nn*(Nn-1)/2
#define TOTE (Bg*Ee)  // 258048
#define SCOLS 576     // padded 514 -> 9*64 so GEMM2 tiles exactly
#define MROWS 8192    // Bg*Nn

typedef __attribute__((ext_vector_type(8))) short bf16x8;
typedef __attribute__((ext_vector_type(4))) float f32x4;

static __device__ __forceinline__ ushort f2bf(float v) {
    __hip_bfloat16 h = __float2bfloat16(v);
    return *(ushort*)&h;
}

// ---------------- prep: WgT->bf16, packed WcatT->bf16, ebias, red init ----------------
// Weights stored TRANSPOSED: WgbT[n][k] (256x320), WcatT[n][k] (576x256).
#define CVT_N (INF * Hd)                  // 81920
#define PACK_N (Hd * SCOLS)               // 147456
__global__ void k_prep(const float* __restrict__ Wg, const float* __restrict__ Wm,
                       const float* __restrict__ Wv, const float* __restrict__ Ww,
                       const float* __restrict__ bm, const float* __restrict__ bv,
                       const float* __restrict__ bw,
                       ushort* __restrict__ WgbT, ushort* __restrict__ WcatT,
                       float* __restrict__ ebias, unsigned* __restrict__ red) {
    int idx = blockIdx.x * 256 + threadIdx.x;
    if (idx == 0) { red[0] = 0u; red[1] = 0u; }
    if (idx < CVT_N) {
        int n = idx / INF, k = idx - n * INF;
        WgbT[idx] = f2bf(Wg[k * Hd + n]);
        return;
    }
    idx -= CVT_N;
    if (idx < PACK_N) {
        int n = idx / Hd, k = idx - n * Hd;   // n = output col, k = reduction
        float v = 0.f;
        if (n < 128)       v = Wm[k * 128 + n];
        else if (n < 256)  v = Wm[(256 + k) * 128 + (n - 128)];
        else if (n < 384)  v = Wv[k * 128 + (n - 256)];
        else if (n < 512)  v = Wv[(256 + k) * 128 + (n - 384)];
        else if (n == 512) v = Ww[k];
        else if (n == 513) v = Ww[256 + k];
        WcatT[idx] = f2bf(v);
        return;
    }
    idx -= PACK_N;
    if (idx >= SCOLS) return;
    float e = 0.f;
    if (idx < 128)                    e = bm[idx];
    else if (idx >= 256 && idx < 384) e = bv[idx - 256];
    else if (idx == 512)              e = bw[0];
    ebias[idx] = e;
}

// ---------------- prefix-mean aggregation: LDS-tiled coalesced scan ----------------
// grid (128 graphs, 5 f-tiles of 64). Stage 64x64 f32 tile coalesced, wave64
// shuffle-scan along nodes per feature column, coalesced bf16 store.
__global__ __launch_bounds__(256) void k_agg(const float* __restrict__ topo,
                                             const float* __restrict__ temp,
                                             ushort* __restrict__ agg) {
    __shared__ float T[64 * 65];
    const int b = blockIdx.x, ft = blockIdx.y;
    const int tid = threadIdx.x;
    const int row = tid >> 2, seg = tid & 3;
    const float* src = (ft == 0) ? (topo + (size_t)(b * Nn + row) * Nn)
                                 : (temp + (size_t)(b * Nn + row) * Tt + (ft - 1) * 64);
    #pragma unroll
    for (int i = 0; i < 4; ++i) {
        float4 v = *(const float4*)(src + seg * 16 + i * 4);
        float* d = &T[row * 65 + seg * 16 + i * 4];
        d[0] = v.x; d[1] = v.y; d[2] = v.z; d[3] = v.w;
    }
    __syncthreads();
    const int w = tid >> 6, lane = tid & 63;
    #pragma unroll
    for (int k = 0; k < 16; ++k) {
        int f = w * 16 + k;
        float x = T[lane * 65 + f];
        float incl = x;
        #pragma unroll
        for (int o = 1; o < 64; o <<= 1) {
            float t = __shfl_up(incl, o);
            if (lane >= o) incl += t;
        }
        float excl = incl - x;
        T[lane * 65 + f] = lane ? excl * __builtin_amdgcn_rcpf((float)lane) : 0.f;
    }
    __syncthreads();
    const int node = tid >> 2, f0 = (tid & 3) * 16;
    ushort tmp[16];
    #pragma unroll
    for (int i = 0; i < 16; ++i) tmp[i] = f2bf(T[node * 65 + f0 + i]);
    ushort* dst = agg + (size_t)(b * Nn + node) * INF + ft * 64 + f0;
    *(uint4*)dst = *(uint4*)tmp;
    *(uint4*)(dst + 8) = *(uint4*)(tmp + 8);
}

// ---------------- bf16 MFMA GEMM, 64x64 tile, BK=64, B pre-transposed ----------------
// A: MxK bf16 row-major. BT: NxK bf16 row-major. K % 64 == 0.
// transC=0: C row-major (Cb bf16 w/ bias+relu, else Cf fp32).
// transC=1: Cf fp32 transposed (Cf[col][row], ld=MROWS), bias per col.
__global__ __launch_bounds__(256) void k_gemm_mfma(const ushort* __restrict__ A,
                                                   const ushort* __restrict__ BT,
                                                   const float* __restrict__ bias,
                                                   ushort* __restrict__ Cb,
                                                   float* __restrict__ Cf,
                                                   int N, int K, int relu, int transC) {
    __shared__ ushort Asl[64 * 72];
    __shared__ ushort Bsl[64 * 72];   // [n][k]
    const int tid = threadIdx.x;
    const int w = tid >> 6, lane = tid & 63;
    const int quad = lane >> 4, r16 = lane & 15;
    const int m0 = blockIdx.y * 64, n0 = blockIdx.x * 64;
    const int row = tid >> 2, seg = tid & 3;   // 16 elems (32B) per thread per tile
    f32x4 acc[4] = {};

    for (int k0 = 0; k0 < K; k0 += 64) {
        const ushort* ap = A + (size_t)(m0 + row) * K + k0 + seg * 16;
        uint4 a0 = ((const uint4*)ap)[0];
        uint4 a1 = ((const uint4*)ap)[1];
        *(uint4*)(Asl + row * 72 + seg * 16)     = a0;
        *(uint4*)(Asl + row * 72 + seg * 16 + 8) = a1;
        const ushort* bp = BT + (size_t)(n0 + row) * K + k0 + seg * 16;
        uint4 b0 = ((const uint4*)bp)[0];
        uint4 b1 = ((const uint4*)bp)[1];
        *(uint4*)(Bsl + row * 72 + seg * 16)     = b0;
        *(uint4*)(Bsl + row * 72 + seg * 16 + 8) = b1;
        __syncthreads();

        bf16x8 af0 = *(const bf16x8*)(Asl + (w * 16 + r16) * 72 + quad * 8);
        bf16x8 af1 = *(const bf16x8*)(Asl + (w * 16 + r16) * 72 + 32 + quad * 8);
        #pragma unroll
        for (int ns = 0; ns < 4; ++ns) {
            bf16x8 bf0 = *(const bf16x8*)(Bsl + (ns * 16 + r16) * 72 + quad * 8);
            bf16x8 bf1 = *(const bf16x8*)(Bsl + (ns * 16 + r16) * 72 + 32 + quad * 8);
            acc[ns] = __builtin_amdgcn_mfma_f32_16x16x32_bf16(af0, bf0, acc[ns], 0, 0, 0);
            acc[ns] = __builtin_amdgcn_mfma_f32_16x16x32_bf16(af1, bf1, acc[ns], 0, 0, 0);
        }
        __syncthreads();
    }

    const int row0 = m0 + w * 16 + quad * 4;
    #pragma unroll
    for (int ns = 0; ns < 4; ++ns) {
        f32x4 a = acc[ns];
        int col = n0 + ns * 16 + r16;
        float bb = bias ? bias[col] : 0.f;
        float vv[4];
        #pragma unroll
        for (int i = 0; i < 4; ++i) {
            float v = a[i] + bb;
            if (relu) v = fmaxf(v, 0.f);
            vv[i] = v;
        }
        if (transC) {
            *(float4*)(Cf + (size_t)col * MROWS + row0) = make_float4(vv[0], vv[1], vv[2], vv[3]);
        } else {
            #pragma unroll
            for (int i = 0; i < 4; ++i) {
                int row2 = row0 + i;
                if (Cb) Cb[(size_t)row2 * N + col] = f2bf(vv[i]);
                else    Cf[(size_t)row2 * N + col] = vv[i];
            }
        }
    }
}

// ---------------- fused edge kernel -> numer + denominator atomic ----------------
// 1280 blocks = 128 graphs x 10 group-pairs (4 groups of 16 nodes, g0<=g1).
// No max-subtraction: logits bounded (<~36), exp safe in fp32.
static __device__ __forceinline__ float eterm(float pm, float qm, float pv, float qv) {
    float m = pm + qm;
    float x = pv + qv;
    float sp = fmaxf(x, 0.f) + __logf(1.f + __expf(-fabsf(x)));
    return m * m * __builtin_amdgcn_rcpf(sp + 1.01e-6f);
}

__global__ __launch_bounds__(256) void k_edge4(const float* __restrict__ ST,
                                               const float* __restrict__ gu,
                                               float* __restrict__ numer,
                                               unsigned* __restrict__ red) {
    __shared__ float L[4][16][132];
    __shared__ float sm[256];
    const int p = blockIdx.x % 10, b = blockIdx.x / 10;
    const int G0v[10] = {0,0,0,0,1,1,1,2,2,3};
    const int G1v[10] = {0,1,2,3,1,2,3,2,3,3};
    const int g0 = G0v[p], g1 = G1v[p];
    const int tid = threadIdx.x;

    #pragma unroll
    for (int rep = 0; rep < 8; ++rep) {
        int it = tid + 256 * rep;              // 0..2047
        int arr = it >> 9;                     // 0..3
        int c = (it >> 2) & 127, nq = it & 3;  // t-row, node-quad
        int g = (arr & 1) ? g1 : g0;
        float4 v = *(const float4*)&ST[(size_t)(arr * 128 + c) * MROWS + b * 64 + g * 16 + nq * 4];
        L[arr][nq * 4 + 0][c] = v.x;
        L[arr][nq * 4 + 1][c] = v.y;
        L[arr][nq * 4 + 2][c] = v.z;
        L[arr][nq * 4 + 3][c] = v.w;
    }
    __syncthreads();

    const int i = tid >> 4, j = tid & 15;
    float acc = 0.f;
    #pragma unroll 4
    for (int t = 0; t < 128; t += 4) {
        float4 mi = *(const float4*)&L[0][i][t];
        float4 mj = *(const float4*)&L[1][j][t];
        float4 vi = *(const float4*)&L[2][i][t];
        float4 vj = *(const float4*)&L[3][j][t];
        acc += eterm(mi.x, mj.x, vi.x, vj.x);
        acc += eterm(mi.y, mj.y, vi.y, vj.y);
        acc += eterm(mi.z, mj.z, vi.z, vj.z);
        acc += eterm(mi.w, mj.w, vi.w, vj.w);
    }

    const int ni = g0 * 16 + i, nj = g1 * 16 + j;
    float en = 0.f;
    if (ni < nj) {
        int e = b * Ee + (ni * (127 - ni)) / 2 + (nj - ni - 1);
        float se = __expf(acc * (-1.f / 256.f));   // exp(-0.5*acc/128)
        float wr = ST[(size_t)512 * MROWS + b * 64 + ni]
                 + ST[(size_t)513 * MROWS + b * 64 + nj];   // bw folded into row 512
        float w  = __builtin_amdgcn_rcpf(1.f + __expf(-wr));
        float g  = -__logf(-__logf(gu[e]));
        en = __expf((w + g) * 2.0f);               // exp(logit), logit <= ~36: safe
        numer[e] = se * en;
    }
    sm[tid] = en; __syncthreads();
    for (int s = 128; s; s >>= 1) {
        if (tid < s) sm[tid] += sm[tid + s];
        __syncthreads();
    }
    if (!tid) atomicAdd((float*)&red[1], sm[0]);
}

// ---------------- final scatter (also zero-fills) ----------------
__global__ void k_out(const float* __restrict__ numer, const unsigned* __restrict__ red,
                      float* __restrict__ out) {
    int idx = blockIdx.x * 256 + threadIdx.x;
    if (idx >= Bg * Nn * Nn) return;
    int b = idx >> 12;
    int rem = idx & 4095;
    int r = rem >> 6, c = rem & 63;
    float v = 0.f;
    if (c > r) {
        int e = b * Ee + (r * (127 - r)) / 2 + (c - r - 1);
        float Sinv = __builtin_amdgcn_rcpf(((const float*)red)[1]);
        v = numer[e] * Sinv;
    }
    out[idx] = v;
}

extern "C" void kernel_launch(void* const* d_in, const int* in_sizes, int n_in,
                              void* d_out, int out_size, void* d_ws, size_t ws_size,
                              hipStream_t stream) {
    const float* topo = (const float*)d_in[0];
    const float* temp = (const float*)d_in[1];
    const float* gu   = (const float*)d_in[2];
    const float* Wg   = (const float*)d_in[3];
    const float* bg   = (const float*)d_in[4];
    const float* Wm   = (const float*)d_in[5];
    const float* bm   = (const float*)d_in[6];
    const float* Wv   = (const float*)d_in[7];
    const float* bv   = (const float*)d_in[8];
    const float* Ww   = (const float*)d_in[9];
    const float* bw   = (const float*)d_in[10];
    float* out = (float*)d_out;

    char* ws = (char*)d_ws;
    size_t off = 0;
    auto carve = [&](size_t bytes) { char* p = ws + off; off = (off + bytes + 255) & ~(size_t)255; return p; };

    // r1 hosts aggb (bf16, 5.2 MB) pre-GEMM1, then S_T[576][8192] f32 (18.9 MB).
    char*   r1    = carve((size_t)SCOLS * MROWS * 4);
    float*  ST    = (float*)r1;
    ushort* aggb  = (ushort*)r1;
    ushort* hb    = (ushort*)carve((size_t)MROWS * Hd * 2);      // 4.19 MB
    ushort* WgbT  = (ushort*)carve((size_t)INF * Hd * 2);        // 0.16 MB
    ushort* WcatT = (ushort*)carve((size_t)Hd * SCOLS * 2);      // 0.29 MB
    float*  ebias = (float*)carve((size_t)SCOLS * 4);
    float*  numer = (float*)carve((size_t)TOTE * 4);             // 1.03 MB
    unsigned* red = (unsigned*)carve(256);

    k_prep<<<(CVT_N + PACK_N + SCOLS + 255) / 256, 256, 0, stream>>>(
        Wg, Wm, Wv, Ww, bm, bv, bw, WgbT, WcatT, ebias, red);
    k_agg<<<dim3(Bg, INF / 64), 256, 0, stream>>>(topo, temp, aggb);
    // GEMM1: hb[8192,256] = relu(aggb[8192,320] @ WgbT^T + bg)
    k_gemm_mfma<<<dim3(Hd / 64, MROWS / 64), 256, 0, stream>>>(
        aggb, WgbT, bg, hb, nullptr, Hd, INF, 1, 0);
    // GEMM2: ST[576][8192] = (hb[8192,256] @ WcatT^T + ebias)^T
    k_gemm_mfma<<<dim3(SCOLS / 64, MROWS / 64), 256, 0, stream>>>(
        hb, WcatT, ebias, nullptr, ST, SCOLS, Hd, 0, 1);
    k_edge4<<<Bg * 10, 256, 0, stream>>>(ST, gu, numer, red);
    k_out<<<(Bg * Nn * Nn + 255) / 256, 256, 0, stream>>>(numer, red, out);
}